// Round 1
// baseline (635.682 us; speedup 1.0000x reference)
//
#include <hip/hip_runtime.h>
#include <hip/hip_bf16.h>

// B=128, N=256, D=H=256. out = [weighted (B*N*D), attention (B*N*N)] fp32.
// rho per batch via Gelfand: 12 normalized squarings (m=4096).
//   squaring 1: fp32 scores -> bf16 M1 (split-bf16 3-MFMA), slot1   [sq_f32bf]
//   squarings 2..12: ONE fused kernel, M resident in LDS (128KB), per-batch
//   block; rho_inv finalized in-block. No intermediate global traffic.
// Projections q/k/vals fused in one launch (vals stored RAW; 1/sigma + bv applied
// in the final GEMM's B-staging). sigma: 1024-thread LDS power iteration.

#define NB 128
#define MAT 65536
#define BIG 8388608LL

typedef __attribute__((ext_vector_type(4))) float floatx4;
typedef __attribute__((ext_vector_type(4))) float f4v;
typedef __attribute__((ext_vector_type(8))) short short8v;
typedef __attribute__((ext_vector_type(4))) short short4v;

__device__ __forceinline__ short f2bf(float x) {
  union { float f; unsigned u; } v; v.f = x;
  unsigned r = v.u + 0x7fff + ((v.u >> 16) & 1);
  return (short)(r >> 16);
}
__device__ __forceinline__ float bf2f(short h) {
  union { unsigned u; float f; } v; v.u = ((unsigned)(unsigned short)h) << 16; return v.f;
}

// ---------------- generic split-bf16 GEMM ------------------------------------------
// smode: 0 alpha=1, 1 alpha=1/scale[bz], 2 alpha=scale[bz*sstride],
//        3 alpha = rho_inv computed inline from partials (scale_ptr = partials base).
template<bool TB, bool BATCHED>
__global__ __launch_bounds__(256) void gemm_mfma(
    const float* __restrict__ A, const float* __restrict__ B, float* __restrict__ C,
    long long sA, long long sB, long long sC,
    const float* __restrict__ bias,
    const float* __restrict__ scale_ptr, int sstride, int smode,
    float* __restrict__ norm_out,
    float* __restrict__ att_out,
    const float* __restrict__ B2, const float* __restrict__ bias2, float* __restrict__ C2,
    const float* __restrict__ B3, float* __restrict__ C3,
    const float* __restrict__ bsc, const float* __restrict__ bsb)
{
  __shared__ short sAhi[128 * 32], sAlo[128 * 32];
  __shared__ short sBhi[128 * 40], sBlo[128 * 40];

  int bz, m0, n0;
  if constexpr (BATCHED) {
    int lin = blockIdx.x;
    int xcd = lin & 7;
    int s = lin >> 3;
    bz = xcd * 16 + (s >> 2);
    int tile = s & 3;
    m0 = (tile >> 1) * 128;
    n0 = (tile & 1) * 128;
  } else {
    bz = 0;
    m0 = blockIdx.y * 128;
    n0 = (blockIdx.x & 1) * 128;
    int sel = blockIdx.x >> 1;
    if (sel == 1) { B = B2; bias = bias2; C = C2; }
    else if (sel == 2) { B = B3; bias = nullptr; C = C3; }
  }
  A += (long long)bz * sA;
  B += (long long)bz * sB;
  C += (long long)bz * sC;

  const int t = threadIdx.x;
  const int lane = t & 63;
  const int wave = t >> 6;
  const int wm = wave >> 1, wn = wave & 1;
  const int q = lane >> 4, c16 = lane & 15;

  float alpha = 1.0f;
  if (smode == 1) alpha = 1.0f / scale_ptr[bz * sstride];
  else if (smode == 2) alpha = scale_ptr[bz * sstride];
  else if (smode == 3) {
    float a2 = 0.f, w = 1.0f;
    #pragma unroll
    for (int i2 = 0; i2 <= 12; i2++) {
      const float* p = scale_ptr + i2 * 512 + bz * 4;
      a2 += w * 0.5f * logf(p[0] + p[1] + p[2] + p[3]);
      w *= 0.5f;
    }
    alpha = expf(-a2);
  }

  float rinv_att = alpha;
  const bool do_att = (att_out != nullptr) && (n0 == 0);

  float binv = 1.0f;
  if (bsc) binv = 1.0f / bsc[0];

  floatx4 acc[4][4];
  #pragma unroll
  for (int i = 0; i < 4; i++)
    #pragma unroll
    for (int j = 0; j < 4; j++)
      acc[i][j] = (floatx4){0.f, 0.f, 0.f, 0.f};

  for (int k0 = 0; k0 < 256; k0 += 32) {
    #pragma unroll
    for (int i = 0; i < 4; i++) {
      int f = t + i * 256;
      int row = f >> 3, c4 = f & 7;
      f4v v = *(const f4v*)(A + (long long)(m0 + row) * 256 + k0 + c4 * 4);
      if (do_att)
        *(f4v*)(att_out + (long long)bz * MAT + (long long)(m0 + row) * 256 + k0 + c4 * 4)
            = v * rinv_att;
      short4v h, l;
      #pragma unroll
      for (int e = 0; e < 4; e++) {
        short hh = f2bf(v[e]);
        h[e] = hh;
        l[e] = f2bf(v[e] - bf2f(hh));
      }
      *(short4v*)&sAhi[row * 32 + c4 * 4] = h;
      *(short4v*)&sAlo[row * 32 + c4 * 4] = l;
    }
    if constexpr (TB) {
      #pragma unroll
      for (int i = 0; i < 4; i++) {
        int f = t + i * 256;
        int row = f >> 3, c4 = f & 7;
        f4v v = *(const f4v*)(B + (long long)(n0 + row) * 256 + k0 + c4 * 4);
        short4v h, l;
        #pragma unroll
        for (int e = 0; e < 4; e++) {
          short hh = f2bf(v[e]);
          h[e] = hh;
          l[e] = f2bf(v[e] - bf2f(hh));
        }
        *(short4v*)&sBhi[row * 40 + c4 * 4] = h;
        *(short4v*)&sBlo[row * 40 + c4 * 4] = l;
      }
      __syncthreads();
    } else {
      __shared__ float sT[32 * 132];
      #pragma unroll
      for (int i = 0; i < 4; i++) {
        int f = t + i * 256;
        int kk = f >> 5, n4 = f & 31;
        f4v v = *(const f4v*)(B + (long long)(k0 + kk) * 256 + n0 + n4 * 4);
        if (bsb) {
          #pragma unroll
          for (int e = 0; e < 4; e++) v[e] = v[e] * binv + bsb[n0 + n4 * 4 + e];
        }
        *(f4v*)&sT[kk * 132 + n4 * 4] = v;
      }
      __syncthreads();
      int n = t & 127, kh = t >> 7;
      short8v h0, h1, l0, l1;
      #pragma unroll
      for (int j = 0; j < 8; j++) {
        float x0 = sT[(kh * 16 + j) * 132 + n];
        float x1 = sT[(kh * 16 + 8 + j) * 132 + n];
        short a0 = f2bf(x0), a1 = f2bf(x1);
        h0[j] = a0; l0[j] = f2bf(x0 - bf2f(a0));
        h1[j] = a1; l1[j] = f2bf(x1 - bf2f(a1));
      }
      *(short8v*)&sBhi[n * 40 + kh * 16] = h0;
      *(short8v*)&sBhi[n * 40 + kh * 16 + 8] = h1;
      *(short8v*)&sBlo[n * 40 + kh * 16] = l0;
      *(short8v*)&sBlo[n * 40 + kh * 16 + 8] = l1;
      __syncthreads();
    }

    short8v ah[4], al[4], bh[4], bl[4];
    #pragma unroll
    for (int fi = 0; fi < 4; fi++) {
      int r = wm * 64 + fi * 16 + c16;
      ah[fi] = *(short8v*)&sAhi[r * 32 + q * 8];
      al[fi] = *(short8v*)&sAlo[r * 32 + q * 8];
    }
    #pragma unroll
    for (int fj = 0; fj < 4; fj++) {
      int r = wn * 64 + fj * 16 + c16;
      bh[fj] = *(short8v*)&sBhi[r * 40 + q * 8];
      bl[fj] = *(short8v*)&sBlo[r * 40 + q * 8];
    }
    #pragma unroll
    for (int fi = 0; fi < 4; fi++)
      #pragma unroll
      for (int fj = 0; fj < 4; fj++) {
        acc[fi][fj] = __builtin_amdgcn_mfma_f32_16x16x32_bf16(al[fi], bh[fj], acc[fi][fj], 0, 0, 0);
        acc[fi][fj] = __builtin_amdgcn_mfma_f32_16x16x32_bf16(ah[fi], bl[fj], acc[fi][fj], 0, 0, 0);
        acc[fi][fj] = __builtin_amdgcn_mfma_f32_16x16x32_bf16(ah[fi], bh[fj], acc[fi][fj], 0, 0, 0);
      }
    __syncthreads();
  }

  float ssq = 0.f;
  #pragma unroll
  for (int fi = 0; fi < 4; fi++) {
    #pragma unroll
    for (int fj = 0; fj < 4; fj++) {
      int col = n0 + wn * 64 + fj * 16 + c16;
      float bb = bias ? bias[col] : 0.f;
      #pragma unroll
      for (int r = 0; r < 4; r++) {
        int row = m0 + wm * 64 + fi * 16 + q * 4 + r;
        float v = acc[fi][fj][r] * alpha + bb;
        C[(long long)row * 256 + col] = v;
        ssq += v * v;
      }
    }
  }

  if (norm_out) {
    float* red = (float*)sAhi;
    red[t] = ssq;
    __syncthreads();
    for (int off = 128; off > 0; off >>= 1) {
      if (t < off) red[t] += red[t + off];
      __syncthreads();
    }
    if (t == 0) {
      int tl = ((m0 >> 7) << 1) | (n0 >> 7);
      norm_out[bz * 4 + tl] = red[0];
    }
  }
}

// ---------------- chain epilogue (used by sq_f32bf) --------------------------------
__device__ __forceinline__ void chain_epilogue(
    short* LB, float* red, floatx4 (&acc)[4][4], float alpha,
    int m0, int n0, int wm, int wn, int q, int c16, int t,
    short* __restrict__ Mout,
    float* __restrict__ nout, int bz, int tile, bool write_out)
{
  __syncthreads();
  float ssq = 0.f;
  #pragma unroll
  for (int fi = 0; fi < 4; fi++)
    #pragma unroll
    for (int fj = 0; fj < 4; fj++) {
      int lcol = wn * 64 + fj * 16 + c16;
      #pragma unroll
      for (int r = 0; r < 4; r++) {
        int lrow = wm * 64 + fi * 16 + q * 4 + r;
        float v = acc[fi][fj][r] * alpha;
        ssq += v * v;
        if (write_out) LB[lrow * 128 + lcol] = f2bf(v);
      }
    }

  if (write_out) {
    __syncthreads();
    int lr = t >> 1, off = (t & 1) * 64;
    #pragma unroll
    for (int jc = 0; jc < 8; jc++)
      *(short8v*)(Mout + (long long)(m0 + lr) * 256 + n0 + off + jc * 8)
          = *(const short8v*)&LB[lr * 128 + off + jc * 8];
  }

  red[t] = ssq;
  __syncthreads();
  for (int off2 = 128; off2 > 0; off2 >>= 1) {
    if (t < off2) red[t] += red[t + off2];
    __syncthreads();
  }
  if (t == 0) nout[bz * 4 + tile] = red[0];
}

// ---------------- squaring 1: fp32 S (split 3-MFMA) -> bf16 M ----------------------
__global__ __launch_bounds__(256) void sq_f32bf(
    const float* __restrict__ S, short* __restrict__ Mo,
    const float* __restrict__ nprev, float* __restrict__ nout)
{
  __shared__ short SM[18432];
  __shared__ float sT[32 * 132];
  __shared__ float red[256];
  short* sAhi = SM;
  short* sAlo = SM + 4096;
  short* sBhi = SM + 8192;
  short* sBlo = SM + 13312;

  int lin = blockIdx.x;
  int xcd = lin & 7, s = lin >> 3;
  int bz = xcd * 16 + (s >> 2);
  int tile = s & 3;
  int m0 = (tile >> 1) * 128, n0 = (tile & 1) * 128;
  const float* A = S + (long long)bz * MAT;

  const int t = threadIdx.x;
  const int lane = t & 63;
  const int wave = t >> 6;
  const int wm = wave >> 1, wn = wave & 1;
  const int q = lane >> 4, c16 = lane & 15;

  floatx4 acc[4][4];
  #pragma unroll
  for (int i = 0; i < 4; i++)
    #pragma unroll
    for (int j = 0; j < 4; j++)
      acc[i][j] = (floatx4){0.f, 0.f, 0.f, 0.f};

  for (int k0 = 0; k0 < 256; k0 += 32) {
    #pragma unroll
    for (int i = 0; i < 4; i++) {
      int f = t + i * 256;
      int row = f >> 3, c4 = f & 7;
      f4v v = *(const f4v*)(A + (long long)(m0 + row) * 256 + k0 + c4 * 4);
      short4v h, l;
      #pragma unroll
      for (int e = 0; e < 4; e++) {
        short hh = f2bf(v[e]);
        h[e] = hh;
        l[e] = f2bf(v[e] - bf2f(hh));
      }
      *(short4v*)&sAhi[row * 32 + c4 * 4] = h;
      *(short4v*)&sAlo[row * 32 + c4 * 4] = l;
    }
    #pragma unroll
    for (int i = 0; i < 4; i++) {
      int f = t + i * 256;
      int kk = f >> 5, n4 = f & 31;
      f4v v = *(const f4v*)(A + (long long)(k0 + kk) * 256 + n0 + n4 * 4);
      *(f4v*)&sT[kk * 132 + n4 * 4] = v;
    }
    __syncthreads();
    {
      int n = t & 127, kh = t >> 7;
      short8v h0, h1, l0, l1;
      #pragma unroll
      for (int j = 0; j < 8; j++) {
        float x0 = sT[(kh * 16 + j) * 132 + n];
        float x1 = sT[(kh * 16 + 8 + j) * 132 + n];
        short a0 = f2bf(x0), a1 = f2bf(x1);
        h0[j] = a0; l0[j] = f2bf(x0 - bf2f(a0));
        h1[j] = a1; l1[j] = f2bf(x1 - bf2f(a1));
      }
      *(short8v*)&sBhi[n * 40 + kh * 16] = h0;
      *(short8v*)&sBhi[n * 40 + kh * 16 + 8] = h1;
      *(short8v*)&sBlo[n * 40 + kh * 16] = l0;
      *(short8v*)&sBlo[n * 40 + kh * 16 + 8] = l1;
    }
    __syncthreads();

    short8v ah[4], al[4], bh[4], bl[4];
    #pragma unroll
    for (int fi = 0; fi < 4; fi++) {
      int r = wm * 64 + fi * 16 + c16;
      ah[fi] = *(short8v*)&sAhi[r * 32 + q * 8];
      al[fi] = *(short8v*)&sAlo[r * 32 + q * 8];
    }
    #pragma unroll
    for (int fj = 0; fj < 4; fj++) {
      int r = wn * 64 + fj * 16 + c16;
      bh[fj] = *(short8v*)&sBhi[r * 40 + q * 8];
      bl[fj] = *(short8v*)&sBlo[r * 40 + q * 8];
    }
    #pragma unroll
    for (int fi = 0; fi < 4; fi++)
      #pragma unroll
      for (int fj = 0; fj < 4; fj++) {
        acc[fi][fj] = __builtin_amdgcn_mfma_f32_16x16x32_bf16(al[fi], bh[fj], acc[fi][fj], 0, 0, 0);
        acc[fi][fj] = __builtin_amdgcn_mfma_f32_16x16x32_bf16(ah[fi], bl[fj], acc[fi][fj], 0, 0, 0);
        acc[fi][fj] = __builtin_amdgcn_mfma_f32_16x16x32_bf16(ah[fi], bh[fj], acc[fi][fj], 0, 0, 0);
      }
    __syncthreads();
  }

  const float* p = nprev + bz * 4;
  float alpha = 1.0f / (p[0] + p[1] + p[2] + p[3]);
  chain_epilogue(SM, red, acc, alpha, m0, n0, wm, wn, q, c16, t,
                 Mo + (long long)bz * MAT, nout, bz, tile, true);
}

// ---------------- squarings 2..12: ONE kernel, LDS-resident M per batch ------------
// 128 blocks x 1024 threads (16 waves, 4x4 grid of 64x64 tiles).
// M: [256][256] bf16, XOR-swizzled (col ^ ((row&7)<<3)) -> conflict-free b128 A-frags.
// Bs: per-32k transposed slice [256][32], chunk-XOR (kh ^ (n&3)) -> b128 B-frags.
// rho_inv = exp(-sum 0.5^{i+1} ln n_i) finalized in-block.
__device__ __forceinline__ int midx(int row, int col) {
  return row * 256 + (col ^ ((row & 7) << 3));
}

__global__ __launch_bounds__(1024, 4) void chain_fused(
    const short* __restrict__ M1, const float* __restrict__ partials,
    float* __restrict__ rho_inv)
{
  __shared__ short M[65536];
  __shared__ short Bs[8192];
  __shared__ float red[16];

  const int bz = blockIdx.x;
  const int t = threadIdx.x;
  const int lane = t & 63;
  const int wave = t >> 6;
  const int wm = wave >> 2, wn = wave & 3;
  const int q = lane >> 4, c16 = lane & 15;
  const int sn = t & 255;      // staging column
  const int skh = t >> 8;      // staging k-octet (0..3)

  // load M1 (bf16 row-major) -> swizzled LDS, coalesced b128
  const short* src = M1 + (long long)bz * MAT;
  #pragma unroll
  for (int i = 0; i < 8; i++) {
    int chunk = t + i * 1024;
    int row = chunk >> 5, col8 = (chunk & 31) * 8;
    short8v v = *(const short8v*)(src + chunk * 8);
    *(short8v*)&M[midx(row, col8)] = v;
  }

  const float* p0 = partials + bz * 4;
  const float* p1 = partials + 512 + bz * 4;
  float n0 = p0[0] + p0[1] + p0[2] + p0[3];
  float nprev = p1[0] + p1[1] + p1[2] + p1[3];
  float a2 = 0.5f * logf(n0) + 0.25f * logf(nprev);
  float w = 0.25f;

  __syncthreads();

  #pragma unroll 1
  for (int s = 2; s <= 12; s++) {
    float alpha = 1.0f / nprev;
    floatx4 acc[4][4];
    #pragma unroll
    for (int i = 0; i < 4; i++)
      #pragma unroll
      for (int j = 0; j < 4; j++)
        acc[i][j] = (floatx4){0.f, 0.f, 0.f, 0.f};

    for (int k0 = 0; k0 < 256; k0 += 32) {
      if (k0) __syncthreads();   // prior B-frag reads done before Bs overwrite
      // stage Bs[n][kk] = M[k0+kk][n]; thread: column sn, k-octet skh
      short8v sv;
      #pragma unroll
      for (int j = 0; j < 8; j++)
        sv[j] = M[midx(k0 + skh * 8 + j, sn)];
      *(short8v*)&Bs[sn * 32 + ((skh ^ (sn & 3)) << 3)] = sv;
      __syncthreads();

      short8v b[4];
      #pragma unroll
      for (int fj = 0; fj < 4; fj++) {
        int n = wn * 64 + fj * 16 + c16;
        b[fj] = *(const short8v*)&Bs[n * 32 + ((q ^ (n & 3)) << 3)];
      }
      #pragma unroll
      for (int fi = 0; fi < 4; fi++) {
        int r = wm * 64 + fi * 16 + c16;
        short8v a = *(const short8v*)&M[midx(r, k0 + q * 8)];
        #pragma unroll
        for (int fj = 0; fj < 4; fj++)
          acc[fi][fj] = __builtin_amdgcn_mfma_f32_16x16x32_bf16(a, b[fj], acc[fi][fj], 0, 0, 0);
      }
    }
    __syncthreads();   // all M/Bs reads done before M overwrite

    float ssq = 0.f;
    #pragma unroll
    for (int fi = 0; fi < 4; fi++)
      #pragma unroll
      for (int fj = 0; fj < 4; fj++) {
        int col = wn * 64 + fj * 16 + c16;
        #pragma unroll
        for (int r = 0; r < 4; r++) {
          int row = wm * 64 + fi * 16 + q * 4 + r;
          float v = acc[fi][fj][r] * alpha;
          ssq += v * v;
          if (s < 12) M[midx(row, col)] = f2bf(v);
        }
      }

    // block-wide norm: wave shuffle reduce -> 16 partials -> broadcast sum
    #pragma unroll
    for (int off = 32; off > 0; off >>= 1)
      ssq += __shfl_xor(ssq, off, 64);
    if (lane == 0) red[wave] = ssq;
    __syncthreads();   // also publishes M writes for next squaring's staging
    float tot = 0.f;
    #pragma unroll
    for (int i = 0; i < 16; i++) tot += red[i];
    w *= 0.5f;
    a2 += w * logf(tot);
    nprev = tot;
  }

  if (t == 0) rho_inv[bz] = expf(-a2);
}

// ---------------- sigma: 1024-thread power iteration, LDS-cached bf16 W ------------
__device__ __forceinline__ float bsum1024(float x, float* red, int t)
{
  red[t] = x; __syncthreads();
  for (int off = 512; off > 0; off >>= 1) {
    if (t < off) red[t] += red[t + off];
    __syncthreads();
  }
  float r = red[0];
  __syncthreads();
  return r;
}

__global__ __launch_bounds__(1024) void sigma_kernel(
    const float* __restrict__ W, const float* __restrict__ u0, float* __restrict__ sigma)
{
  __shared__ short Wl[65536];
  __shared__ float u[256], v[256], red[1024];
  int t = threadIdx.x;
  int r = t & 255, seg = t >> 8;
  const float eps = 1e-12f;

  #pragma unroll
  for (int i = 0; i < 16; i++) {
    int idx = (i * 1024 + t) * 4;
    f4v w = *(const f4v*)(W + idx);
    short4v h;
    #pragma unroll
    for (int e = 0; e < 4; e++) h[e] = f2bf(w[e]);
    *(short4v*)&Wl[idx] = h;
  }

  float x = (t < 256) ? u0[t] : 0.f;
  float nrm = sqrtf(bsum1024(x * x, red, t));
  if (t < 256) u[t] = x / (nrm + eps);
  __syncthreads();

  for (int it = 0; it < 5; it++) {
    float sv = 0.f;
    #pragma unroll 8
    for (int j = 0; j < 64; j++) {
      int h = seg * 64 + j;
      sv = fmaf(bf2f(Wl[h * 256 + r]), u[h], sv);
    }
    red[t] = sv; __syncthreads();
    float vr = 0.f;
    if (t < 256) vr = red[t] + red[256 + t] + red[512 + t] + red[768 + t];
    __syncthreads();
    nrm = sqrtf(bsum1024(t < 256 ? vr * vr : 0.f, red, t));
    if (t < 256) v[t] = vr / (nrm + eps);
    __syncthreads();
    if (it < 4) {
      float su = 0.f;
      #pragma unroll
      for (int j = 0; j < 16; j++) {
        short4v w4 = *(const short4v*)&Wl[r * 256 + seg * 64 + j * 4];
        const float* vv = &v[seg * 64 + j * 4];
        su += bf2f(w4[0]) * vv[0] + bf2f(w4[1]) * vv[1]
            + bf2f(w4[2]) * vv[2] + bf2f(w4[3]) * vv[3];
      }
      red[t] = su; __syncthreads();
      float ur = 0.f;
      if (t < 256) ur = red[t] + red[256 + t] + red[512 + t] + red[768 + t];
      __syncthreads();
      nrm = sqrtf(bsum1024(t < 256 ? ur * ur : 0.f, red, t));
      if (t < 256) u[t] = ur / (nrm + eps);
      __syncthreads();
    }
  }

  float z = 0.f;
  #pragma unroll
  for (int j = 0; j < 16; j++) {
    f4v w = *(const f4v*)(W + r * 256 + seg * 64 + j * 4);
    const float* vv = &v[seg * 64 + j * 4];
    z += w[0] * vv[0] + w[1] * vv[1] + w[2] * vv[2] + w[3] * vv[3];
  }
  red[t] = z; __syncthreads();
  float zr = 0.f;
  if (t < 256) zr = red[t] + red[256 + t] + red[512 + t] + red[768 + t];
  __syncthreads();
  float zz = bsum1024(t < 256 ? zr * zr : 0.f, red, t);
  if (t == 0) sigma[0] = sqrtf(zz);
}

extern "C" void kernel_launch(void* const* d_in, const int* in_sizes, int n_in,
                              void* d_out, int out_size, void* d_ws, size_t ws_size,
                              hipStream_t stream)
{
  const float* x  = (const float*)d_in[0];
  const float* Wq = (const float*)d_in[1];
  const float* bq = (const float*)d_in[2];
  const float* Wk = (const float*)d_in[3];
  const float* bk = (const float*)d_in[4];
  const float* Wv = (const float*)d_in[5];
  const float* bv = (const float*)d_in[6];
  const float* u0 = (const float*)d_in[7];

  float* out  = (float*)d_out;
  float* out0 = out;             // q -> M scratch -> weighted
  float* out1 = out + BIG;       // k -> attention
  short* out0s = (short*)out0;

  float* ws         = (float*)d_ws;
  float* scores_buf = ws;          // [B,N,N] fp32 raw scores
  float* vals_buf   = ws + BIG;    // [B,N,D] RAW x@Wv^T (no sigma, no bias)
  float* partials   = ws + 2 * BIG;   // slots 0,1 used: [2][128][4] per-tile norm^2
  float* sigma      = partials + 13 * 512;
  float* rho_inv    = partials + 1024;  // 128 floats (old slot-2 space)

  dim3 blk(256);

  // 1) fused projections: q -> out0, k -> out1, raw vals -> ws
  gemm_mfma<true, false><<<dim3(6, 256, 1), blk, 0, stream>>>(
      x, Wq, out0, 0, 0, 0, bq, nullptr, 0, 0, nullptr, nullptr,
      Wk, bk, out1, Wv, vals_buf, nullptr, nullptr);

  // 2) scores = q @ k^T -> ws (fp32), per-tile norm^2 -> slot 0
  gemm_mfma<true, true><<<dim3(512, 1, 1), blk, 0, stream>>>(
      out0, out1, scores_buf, MAT, MAT, MAT, nullptr, nullptr, 0, 0, partials,
      nullptr, nullptr, nullptr, nullptr, nullptr, nullptr, nullptr, nullptr);

  // 3) sigma power iteration
  sigma_kernel<<<1, dim3(1024), 0, stream>>>(Wv, u0, sigma);

  // 4) squaring 1: S (fp32, split) -> bf16 M1 in out0s, norm slot 1
  sq_f32bf<<<dim3(512, 1, 1), blk, 0, stream>>>(scores_buf, out0s, partials, partials + 512);

  // 5) squarings 2..12 fused, LDS-resident; writes rho_inv[bz]
  chain_fused<<<dim3(128, 1, 1), dim3(1024, 1, 1), 0, stream>>>(out0s, partials, rho_inv);

  // 6) final: weighted = (S @ (vals/sigma + bv)) * rho_inv -> out0,
  //    attention = S * rho_inv -> out1 (A-staging). alpha = rho_inv[bz] (smode 2).
  gemm_mfma<false, true><<<dim3(512, 1, 1), blk, 0, stream>>>(
      scores_buf, vals_buf, out0, MAT, MAT, MAT, nullptr, rho_inv, 1, 2, nullptr,
      out1, nullptr, nullptr, nullptr, nullptr, nullptr, sigma, bv);
}

// Round 2
// 602.977 us; speedup vs baseline: 1.0542x; 1.0542x over previous
//
#include <hip/hip_runtime.h>
#include <hip/hip_bf16.h>

// B=128, N=256, D=H=256. out = [weighted (B*N*D), attention (B*N*N)] fp32.
// rho per batch via Gelfand: 12 normalized squarings (m=4096).
//   squaring 1: fp32 scores -> bf16 M1 (split-bf16 3-MFMA), slot1   [sq_f32bf]
//   squarings 2..12: ONE fused kernel, M resident in LDS (128KB), per-batch
//   block; rho_inv finalized in-block. v2: 512 threads (2 waves/SIMD -> 256-reg
//   cap, no spill), (row>>1)&7 swizzle, quad-packed epilogue, stride-40 Bs.
// Projections q/k/vals fused in one launch (vals stored RAW; 1/sigma + bv applied
// in the final GEMM's B-staging). sigma: 1024-thread LDS power iteration.

#define NB 128
#define MAT 65536
#define BIG 8388608LL

typedef __attribute__((ext_vector_type(4))) float floatx4;
typedef __attribute__((ext_vector_type(4))) float f4v;
typedef __attribute__((ext_vector_type(8))) short short8v;
typedef __attribute__((ext_vector_type(4))) short short4v;
typedef __attribute__((ext_vector_type(2))) unsigned uintx2;

__device__ __forceinline__ short f2bf(float x) {
  union { float f; unsigned u; } v; v.f = x;
  unsigned r = v.u + 0x7fff + ((v.u >> 16) & 1);
  return (short)(r >> 16);
}
__device__ __forceinline__ float bf2f(short h) {
  union { unsigned u; float f; } v; v.u = ((unsigned)(unsigned short)h) << 16; return v.f;
}

// ---------------- generic split-bf16 GEMM ------------------------------------------
template<bool TB, bool BATCHED>
__global__ __launch_bounds__(256) void gemm_mfma(
    const float* __restrict__ A, const float* __restrict__ B, float* __restrict__ C,
    long long sA, long long sB, long long sC,
    const float* __restrict__ bias,
    const float* __restrict__ scale_ptr, int sstride, int smode,
    float* __restrict__ norm_out,
    float* __restrict__ att_out,
    const float* __restrict__ B2, const float* __restrict__ bias2, float* __restrict__ C2,
    const float* __restrict__ B3, float* __restrict__ C3,
    const float* __restrict__ bsc, const float* __restrict__ bsb)
{
  __shared__ short sAhi[128 * 32], sAlo[128 * 32];
  __shared__ short sBhi[128 * 40], sBlo[128 * 40];

  int bz, m0, n0;
  if constexpr (BATCHED) {
    int lin = blockIdx.x;
    int xcd = lin & 7;
    int s = lin >> 3;
    bz = xcd * 16 + (s >> 2);
    int tile = s & 3;
    m0 = (tile >> 1) * 128;
    n0 = (tile & 1) * 128;
  } else {
    bz = 0;
    m0 = blockIdx.y * 128;
    n0 = (blockIdx.x & 1) * 128;
    int sel = blockIdx.x >> 1;
    if (sel == 1) { B = B2; bias = bias2; C = C2; }
    else if (sel == 2) { B = B3; bias = nullptr; C = C3; }
  }
  A += (long long)bz * sA;
  B += (long long)bz * sB;
  C += (long long)bz * sC;

  const int t = threadIdx.x;
  const int lane = t & 63;
  const int wave = t >> 6;
  const int wm = wave >> 1, wn = wave & 1;
  const int q = lane >> 4, c16 = lane & 15;

  float alpha = 1.0f;
  if (smode == 1) alpha = 1.0f / scale_ptr[bz * sstride];
  else if (smode == 2) alpha = scale_ptr[bz * sstride];
  else if (smode == 3) {
    float a2 = 0.f, w = 1.0f;
    #pragma unroll
    for (int i2 = 0; i2 <= 12; i2++) {
      const float* p = scale_ptr + i2 * 512 + bz * 4;
      a2 += w * 0.5f * logf(p[0] + p[1] + p[2] + p[3]);
      w *= 0.5f;
    }
    alpha = expf(-a2);
  }

  float rinv_att = alpha;
  const bool do_att = (att_out != nullptr) && (n0 == 0);

  float binv = 1.0f;
  if (bsc) binv = 1.0f / bsc[0];

  floatx4 acc[4][4];
  #pragma unroll
  for (int i = 0; i < 4; i++)
    #pragma unroll
    for (int j = 0; j < 4; j++)
      acc[i][j] = (floatx4){0.f, 0.f, 0.f, 0.f};

  for (int k0 = 0; k0 < 256; k0 += 32) {
    #pragma unroll
    for (int i = 0; i < 4; i++) {
      int f = t + i * 256;
      int row = f >> 3, c4 = f & 7;
      f4v v = *(const f4v*)(A + (long long)(m0 + row) * 256 + k0 + c4 * 4);
      if (do_att)
        *(f4v*)(att_out + (long long)bz * MAT + (long long)(m0 + row) * 256 + k0 + c4 * 4)
            = v * rinv_att;
      short4v h, l;
      #pragma unroll
      for (int e = 0; e < 4; e++) {
        short hh = f2bf(v[e]);
        h[e] = hh;
        l[e] = f2bf(v[e] - bf2f(hh));
      }
      *(short4v*)&sAhi[row * 32 + c4 * 4] = h;
      *(short4v*)&sAlo[row * 32 + c4 * 4] = l;
    }
    if constexpr (TB) {
      #pragma unroll
      for (int i = 0; i < 4; i++) {
        int f = t + i * 256;
        int row = f >> 3, c4 = f & 7;
        f4v v = *(const f4v*)(B + (long long)(n0 + row) * 256 + k0 + c4 * 4);
        short4v h, l;
        #pragma unroll
        for (int e = 0; e < 4; e++) {
          short hh = f2bf(v[e]);
          h[e] = hh;
          l[e] = f2bf(v[e] - bf2f(hh));
        }
        *(short4v*)&sBhi[row * 40 + c4 * 4] = h;
        *(short4v*)&sBlo[row * 40 + c4 * 4] = l;
      }
      __syncthreads();
    } else {
      __shared__ float sT[32 * 132];
      #pragma unroll
      for (int i = 0; i < 4; i++) {
        int f = t + i * 256;
        int kk = f >> 5, n4 = f & 31;
        f4v v = *(const f4v*)(B + (long long)(k0 + kk) * 256 + n0 + n4 * 4);
        if (bsb) {
          #pragma unroll
          for (int e = 0; e < 4; e++) v[e] = v[e] * binv + bsb[n0 + n4 * 4 + e];
        }
        *(f4v*)&sT[kk * 132 + n4 * 4] = v;
      }
      __syncthreads();
      int n = t & 127, kh = t >> 7;
      short8v h0, h1, l0, l1;
      #pragma unroll
      for (int j = 0; j < 8; j++) {
        float x0 = sT[(kh * 16 + j) * 132 + n];
        float x1 = sT[(kh * 16 + 8 + j) * 132 + n];
        short a0 = f2bf(x0), a1 = f2bf(x1);
        h0[j] = a0; l0[j] = f2bf(x0 - bf2f(a0));
        h1[j] = a1; l1[j] = f2bf(x1 - bf2f(a1));
      }
      *(short8v*)&sBhi[n * 40 + kh * 16] = h0;
      *(short8v*)&sBhi[n * 40 + kh * 16 + 8] = h1;
      *(short8v*)&sBlo[n * 40 + kh * 16] = l0;
      *(short8v*)&sBlo[n * 40 + kh * 16 + 8] = l1;
      __syncthreads();
    }

    short8v ah[4], al[4], bh[4], bl[4];
    #pragma unroll
    for (int fi = 0; fi < 4; fi++) {
      int r = wm * 64 + fi * 16 + c16;
      ah[fi] = *(short8v*)&sAhi[r * 32 + q * 8];
      al[fi] = *(short8v*)&sAlo[r * 32 + q * 8];
    }
    #pragma unroll
    for (int fj = 0; fj < 4; fj++) {
      int r = wn * 64 + fj * 16 + c16;
      bh[fj] = *(short8v*)&sBhi[r * 40 + q * 8];
      bl[fj] = *(short8v*)&sBlo[r * 40 + q * 8];
    }
    #pragma unroll
    for (int fi = 0; fi < 4; fi++)
      #pragma unroll
      for (int fj = 0; fj < 4; fj++) {
        acc[fi][fj] = __builtin_amdgcn_mfma_f32_16x16x32_bf16(al[fi], bh[fj], acc[fi][fj], 0, 0, 0);
        acc[fi][fj] = __builtin_amdgcn_mfma_f32_16x16x32_bf16(ah[fi], bl[fj], acc[fi][fj], 0, 0, 0);
        acc[fi][fj] = __builtin_amdgcn_mfma_f32_16x16x32_bf16(ah[fi], bh[fj], acc[fi][fj], 0, 0, 0);
      }
    __syncthreads();
  }

  float ssq = 0.f;
  #pragma unroll
  for (int fi = 0; fi < 4; fi++) {
    #pragma unroll
    for (int fj = 0; fj < 4; fj++) {
      int col = n0 + wn * 64 + fj * 16 + c16;
      float bb = bias ? bias[col] : 0.f;
      #pragma unroll
      for (int r = 0; r < 4; r++) {
        int row = m0 + wm * 64 + fi * 16 + q * 4 + r;
        float v = acc[fi][fj][r] * alpha + bb;
        C[(long long)row * 256 + col] = v;
        ssq += v * v;
      }
    }
  }

  if (norm_out) {
    float* red = (float*)sAhi;
    red[t] = ssq;
    __syncthreads();
    for (int off = 128; off > 0; off >>= 1) {
      if (t < off) red[t] += red[t + off];
      __syncthreads();
    }
    if (t == 0) {
      int tl = ((m0 >> 7) << 1) | (n0 >> 7);
      norm_out[bz * 4 + tl] = red[0];
    }
  }
}

// ---------------- chain epilogue (used by sq_f32bf) --------------------------------
__device__ __forceinline__ void chain_epilogue(
    short* LB, float* red, floatx4 (&acc)[4][4], float alpha,
    int m0, int n0, int wm, int wn, int q, int c16, int t,
    short* __restrict__ Mout,
    float* __restrict__ nout, int bz, int tile, bool write_out)
{
  __syncthreads();
  float ssq = 0.f;
  #pragma unroll
  for (int fi = 0; fi < 4; fi++)
    #pragma unroll
    for (int fj = 0; fj < 4; fj++) {
      int lcol = wn * 64 + fj * 16 + c16;
      #pragma unroll
      for (int r = 0; r < 4; r++) {
        int lrow = wm * 64 + fi * 16 + q * 4 + r;
        float v = acc[fi][fj][r] * alpha;
        ssq += v * v;
        if (write_out) LB[lrow * 128 + lcol] = f2bf(v);
      }
    }

  if (write_out) {
    __syncthreads();
    int lr = t >> 1, off = (t & 1) * 64;
    #pragma unroll
    for (int jc = 0; jc < 8; jc++)
      *(short8v*)(Mout + (long long)(m0 + lr) * 256 + n0 + off + jc * 8)
          = *(const short8v*)&LB[lr * 128 + off + jc * 8];
  }

  red[t] = ssq;
  __syncthreads();
  for (int off2 = 128; off2 > 0; off2 >>= 1) {
    if (t < off2) red[t] += red[t + off2];
    __syncthreads();
  }
  if (t == 0) nout[bz * 4 + tile] = red[0];
}

// ---------------- squaring 1: fp32 S (split 3-MFMA) -> bf16 M ----------------------
__global__ __launch_bounds__(256) void sq_f32bf(
    const float* __restrict__ S, short* __restrict__ Mo,
    const float* __restrict__ nprev, float* __restrict__ nout)
{
  __shared__ short SM[18432];
  __shared__ float sT[32 * 132];
  __shared__ float red[256];
  short* sAhi = SM;
  short* sAlo = SM + 4096;
  short* sBhi = SM + 8192;
  short* sBlo = SM + 13312;

  int lin = blockIdx.x;
  int xcd = lin & 7, s = lin >> 3;
  int bz = xcd * 16 + (s >> 2);
  int tile = s & 3;
  int m0 = (tile >> 1) * 128, n0 = (tile & 1) * 128;
  const float* A = S + (long long)bz * MAT;

  const int t = threadIdx.x;
  const int lane = t & 63;
  const int wave = t >> 6;
  const int wm = wave >> 1, wn = wave & 1;
  const int q = lane >> 4, c16 = lane & 15;

  floatx4 acc[4][4];
  #pragma unroll
  for (int i = 0; i < 4; i++)
    #pragma unroll
    for (int j = 0; j < 4; j++)
      acc[i][j] = (floatx4){0.f, 0.f, 0.f, 0.f};

  for (int k0 = 0; k0 < 256; k0 += 32) {
    #pragma unroll
    for (int i = 0; i < 4; i++) {
      int f = t + i * 256;
      int row = f >> 3, c4 = f & 7;
      f4v v = *(const f4v*)(A + (long long)(m0 + row) * 256 + k0 + c4 * 4);
      short4v h, l;
      #pragma unroll
      for (int e = 0; e < 4; e++) {
        short hh = f2bf(v[e]);
        h[e] = hh;
        l[e] = f2bf(v[e] - bf2f(hh));
      }
      *(short4v*)&sAhi[row * 32 + c4 * 4] = h;
      *(short4v*)&sAlo[row * 32 + c4 * 4] = l;
    }
    #pragma unroll
    for (int i = 0; i < 4; i++) {
      int f = t + i * 256;
      int kk = f >> 5, n4 = f & 31;
      f4v v = *(const f4v*)(A + (long long)(k0 + kk) * 256 + n0 + n4 * 4);
      *(f4v*)&sT[kk * 132 + n4 * 4] = v;
    }
    __syncthreads();
    {
      int n = t & 127, kh = t >> 7;
      short8v h0, h1, l0, l1;
      #pragma unroll
      for (int j = 0; j < 8; j++) {
        float x0 = sT[(kh * 16 + j) * 132 + n];
        float x1 = sT[(kh * 16 + 8 + j) * 132 + n];
        short a0 = f2bf(x0), a1 = f2bf(x1);
        h0[j] = a0; l0[j] = f2bf(x0 - bf2f(a0));
        h1[j] = a1; l1[j] = f2bf(x1 - bf2f(a1));
      }
      *(short8v*)&sBhi[n * 40 + kh * 16] = h0;
      *(short8v*)&sBhi[n * 40 + kh * 16 + 8] = h1;
      *(short8v*)&sBlo[n * 40 + kh * 16] = l0;
      *(short8v*)&sBlo[n * 40 + kh * 16 + 8] = l1;
    }
    __syncthreads();

    short8v ah[4], al[4], bh[4], bl[4];
    #pragma unroll
    for (int fi = 0; fi < 4; fi++) {
      int r = wm * 64 + fi * 16 + c16;
      ah[fi] = *(short8v*)&sAhi[r * 32 + q * 8];
      al[fi] = *(short8v*)&sAlo[r * 32 + q * 8];
    }
    #pragma unroll
    for (int fj = 0; fj < 4; fj++) {
      int r = wn * 64 + fj * 16 + c16;
      bh[fj] = *(short8v*)&sBhi[r * 40 + q * 8];
      bl[fj] = *(short8v*)&sBlo[r * 40 + q * 8];
    }
    #pragma unroll
    for (int fi = 0; fi < 4; fi++)
      #pragma unroll
      for (int fj = 0; fj < 4; fj++) {
        acc[fi][fj] = __builtin_amdgcn_mfma_f32_16x16x32_bf16(al[fi], bh[fj], acc[fi][fj], 0, 0, 0);
        acc[fi][fj] = __builtin_amdgcn_mfma_f32_16x16x32_bf16(ah[fi], bl[fj], acc[fi][fj], 0, 0, 0);
        acc[fi][fj] = __builtin_amdgcn_mfma_f32_16x16x32_bf16(ah[fi], bh[fj], acc[fi][fj], 0, 0, 0);
      }
    __syncthreads();
  }

  const float* p = nprev + bz * 4;
  float alpha = 1.0f / (p[0] + p[1] + p[2] + p[3]);
  chain_epilogue(SM, red, acc, alpha, m0, n0, wm, wn, q, c16, t,
                 Mo + (long long)bz * MAT, nout, bz, tile, true);
}

// ---------------- squarings 2..12: ONE kernel, LDS-resident M per batch ------------
// v2: 128 blocks x 512 threads (8 waves, 2x4 grid of 128x64 tiles).
//   - 2 waves/SIMD -> 256-VGPR cap: acc[8][4] (128) + working set fits, NO SPILL
//     (v1 spilled at the 128-cap: 255MB scratch FETCH, MfmaUtil 5.8%).
//   - M: [256][256] bf16, key=(row>>1)&7 XOR at 16B granularity: b128 A-frags at
//     BW floor AND conflict-free quad-packed epilogue writes.
//   - Bs: [256][40] (16B-aligned rows), octet pos kq^((n>>3)&3): staging writes
//     spread over all 8 bank-slots (v1's pattern was 16-way conflicted).
//   - staging reads: b32 column-pairs (XOR-permutation, conflict-free).
//   - epilogue: shfl_xor(1),(2) pack 4 cols -> masked b64 write by every 4th lane.
__device__ __forceinline__ int midx2(int row, int col) {
  return row * 256 + (col ^ (((row >> 1) & 7) << 3));
}

__global__ __launch_bounds__(512, 2) void chain_fused(
    const short* __restrict__ M1, const float* __restrict__ partials,
    float* __restrict__ rho_inv)
{
  __shared__ short M[65536];
  __shared__ short Bs[10240];       // 256 rows x 40 shorts (80B, 16B-aligned)
  __shared__ float red[8];

  const int bz = blockIdx.x;
  const int t = threadIdx.x;
  const int lane = t & 63;
  const int wave = t >> 6;
  const int wm = wave >> 2, wn = wave & 3;     // 2 x 4 wave grid
  const int q = lane >> 4, c16 = lane & 15;
  const int sp = t & 127;          // staging column-pair (cols 2sp, 2sp+1)
  const int skq = t >> 7;          // staging k-octet (0..3)

  // load M1 (bf16 row-major) -> swizzled LDS, coalesced b128
  const short* src = M1 + (long long)bz * MAT;
  #pragma unroll
  for (int i = 0; i < 16; i++) {
    int chunk = t + i * 512;
    int row = chunk >> 5, col8 = (chunk & 31) * 8;
    short8v v = *(const short8v*)(src + chunk * 8);
    *(short8v*)&M[midx2(row, col8)] = v;
  }

  const float* p0 = partials + bz * 4;
  const float* p1 = partials + 512 + bz * 4;
  float nrm0 = p0[0] + p0[1] + p0[2] + p0[3];
  float nprev = p1[0] + p1[1] + p1[2] + p1[3];
  float a2 = 0.5f * logf(nrm0) + 0.25f * logf(nprev);
  float w = 0.25f;

  __syncthreads();

  #pragma unroll 1
  for (int s = 2; s <= 12; s++) {
    float alpha = 1.0f / nprev;
    floatx4 acc[8][4];
    #pragma unroll
    for (int i = 0; i < 8; i++)
      #pragma unroll
      for (int j = 0; j < 4; j++)
        acc[i][j] = (floatx4){0.f, 0.f, 0.f, 0.f};

    for (int k0 = 0; k0 < 256; k0 += 32) {
      if (k0) __syncthreads();   // prior B-frag reads done before Bs overwrite
      // stage Bs[n][kk] = M[k0+kk][n]; thread: col-pair sp, k-octet skq
      short8v sv0, sv1;
      #pragma unroll
      for (int j = 0; j < 8; j++) {
        int row = k0 + skq * 8 + j;
        int key8 = ((row >> 1) & 7) << 3;
        unsigned dw = *(const unsigned*)&M[row * 256 + ((2 * sp) ^ key8)];
        sv0[j] = (short)(dw & 0xffff);
        sv1[j] = (short)(dw >> 16);
      }
      int g = (sp >> 2) & 3;     // octet-position XOR key (same for rows 2sp,2sp+1)
      *(short8v*)&Bs[(2 * sp) * 40 + ((skq ^ g) << 3)] = sv0;
      *(short8v*)&Bs[(2 * sp + 1) * 40 + ((skq ^ g) << 3)] = sv1;
      __syncthreads();

      short8v b[4];
      #pragma unroll
      for (int fj = 0; fj < 4; fj++) {
        int n = wn * 64 + fj * 16 + c16;
        b[fj] = *(const short8v*)&Bs[n * 40 + ((q ^ ((n >> 3) & 3)) << 3)];
      }
      #pragma unroll
      for (int fi = 0; fi < 8; fi++) {
        int r = wm * 128 + fi * 16 + c16;
        short8v a = *(const short8v*)&M[midx2(r, k0 + q * 8)];
        #pragma unroll
        for (int fj = 0; fj < 4; fj++)
          acc[fi][fj] = __builtin_amdgcn_mfma_f32_16x16x32_bf16(a, b[fj], acc[fi][fj], 0, 0, 0);
      }
    }
    __syncthreads();   // all M/Bs reads done before M overwrite

    float ssq = 0.f;
    const bool wr = (s < 12);
    #pragma unroll
    for (int fi = 0; fi < 8; fi++)
      #pragma unroll
      for (int fj = 0; fj < 4; fj++) {
        #pragma unroll
        for (int r = 0; r < 4; r++) {
          int row = wm * 128 + fi * 16 + q * 4 + r;
          float v = acc[fi][fj][r] * alpha;
          ssq += v * v;
          if (wr) {
            // quad-pack 4 adjacent cols across lanes c16, c16^1, c16^2, c16^3
            unsigned bf = (unsigned)(unsigned short)f2bf(v);
            unsigned o1 = (unsigned)__shfl_xor((int)bf, 1, 64);
            unsigned u01 = (c16 & 1) ? ((o1 & 0xffffu) | (bf << 16))
                                     : ((bf & 0xffffu) | (o1 << 16));
            unsigned u2 = (unsigned)__shfl_xor((int)u01, 2, 64);
            if ((c16 & 3) == 0) {
              int col = wn * 64 + fj * 16 + c16;   // multiple of 4
              uintx2 quad; quad[0] = u01; quad[1] = u2;
              *(uintx2*)&M[midx2(row, col)] = quad;
            }
          }
        }
      }

    // block-wide norm: wave shuffle reduce -> 8 partials -> broadcast sum
    #pragma unroll
    for (int off = 32; off > 0; off >>= 1)
      ssq += __shfl_xor(ssq, off, 64);
    if (lane == 0) red[wave] = ssq;
    __syncthreads();   // also publishes M writes for next squaring's staging
    float tot = 0.f;
    #pragma unroll
    for (int i = 0; i < 8; i++) tot += red[i];
    w *= 0.5f;
    a2 += w * logf(tot);
    nprev = tot;
  }

  if (t == 0) rho_inv[bz] = expf(-a2);
}

// ---------------- sigma: 1024-thread power iteration, LDS-cached bf16 W ------------
__device__ __forceinline__ float bsum1024(float x, float* red, int t)
{
  red[t] = x; __syncthreads();
  for (int off = 512; off > 0; off >>= 1) {
    if (t < off) red[t] += red[t + off];
    __syncthreads();
  }
  float r = red[0];
  __syncthreads();
  return r;
}

__global__ __launch_bounds__(1024) void sigma_kernel(
    const float* __restrict__ W, const float* __restrict__ u0, float* __restrict__ sigma)
{
  __shared__ short Wl[65536];
  __shared__ float u[256], v[256], red[1024];
  int t = threadIdx.x;
  int r = t & 255, seg = t >> 8;
  const float eps = 1e-12f;

  #pragma unroll
  for (int i = 0; i < 16; i++) {
    int idx = (i * 1024 + t) * 4;
    f4v w = *(const f4v*)(W + idx);
    short4v h;
    #pragma unroll
    for (int e = 0; e < 4; e++) h[e] = f2bf(w[e]);
    *(short4v*)&Wl[idx] = h;
  }

  float x = (t < 256) ? u0[t] : 0.f;
  float nrm = sqrtf(bsum1024(x * x, red, t));
  if (t < 256) u[t] = x / (nrm + eps);
  __syncthreads();

  for (int it = 0; it < 5; it++) {
    float sv = 0.f;
    #pragma unroll 8
    for (int j = 0; j < 64; j++) {
      int h = seg * 64 + j;
      sv = fmaf(bf2f(Wl[h * 256 + r]), u[h], sv);
    }
    red[t] = sv; __syncthreads();
    float vr = 0.f;
    if (t < 256) vr = red[t] + red[256 + t] + red[512 + t] + red[768 + t];
    __syncthreads();
    nrm = sqrtf(bsum1024(t < 256 ? vr * vr : 0.f, red, t));
    if (t < 256) v[t] = vr / (nrm + eps);
    __syncthreads();
    if (it < 4) {
      float su = 0.f;
      #pragma unroll
      for (int j = 0; j < 16; j++) {
        short4v w4 = *(const short4v*)&Wl[r * 256 + seg * 64 + j * 4];
        const float* vv = &v[seg * 64 + j * 4];
        su += bf2f(w4[0]) * vv[0] + bf2f(w4[1]) * vv[1]
            + bf2f(w4[2]) * vv[2] + bf2f(w4[3]) * vv[3];
      }
      red[t] = su; __syncthreads();
      float ur = 0.f;
      if (t < 256) ur = red[t] + red[256 + t] + red[512 + t] + red[768 + t];
      __syncthreads();
      nrm = sqrtf(bsum1024(t < 256 ? ur * ur : 0.f, red, t));
      if (t < 256) u[t] = ur / (nrm + eps);
      __syncthreads();
    }
  }

  float z = 0.f;
  #pragma unroll
  for (int j = 0; j < 16; j++) {
    f4v w = *(const f4v*)(W + r * 256 + seg * 64 + j * 4);
    const float* vv = &v[seg * 64 + j * 4];
    z += w[0] * vv[0] + w[1] * vv[1] + w[2] * vv[2] + w[3] * vv[3];
  }
  red[t] = z; __syncthreads();
  float zr = 0.f;
  if (t < 256) zr = red[t] + red[256 + t] + red[512 + t] + red[768 + t];
  __syncthreads();
  float zz = bsum1024(t < 256 ? zr * zr : 0.f, red, t);
  if (t == 0) sigma[0] = sqrtf(zz);
}

extern "C" void kernel_launch(void* const* d_in, const int* in_sizes, int n_in,
                              void* d_out, int out_size, void* d_ws, size_t ws_size,
                              hipStream_t stream)
{
  const float* x  = (const float*)d_in[0];
  const float* Wq = (const float*)d_in[1];
  const float* bq = (const float*)d_in[2];
  const float* Wk = (const float*)d_in[3];
  const float* bk = (const float*)d_in[4];
  const float* Wv = (const float*)d_in[5];
  const float* bv = (const float*)d_in[6];
  const float* u0 = (const float*)d_in[7];

  float* out  = (float*)d_out;
  float* out0 = out;             // q -> M scratch -> weighted
  float* out1 = out + BIG;       // k -> attention
  short* out0s = (short*)out0;

  float* ws         = (float*)d_ws;
  float* scores_buf = ws;          // [B,N,N] fp32 raw scores
  float* vals_buf   = ws + BIG;    // [B,N,D] RAW x@Wv^T (no sigma, no bias)
  float* partials   = ws + 2 * BIG;   // slots 0,1 used: [2][128][4] per-tile norm^2
  float* sigma      = partials + 13 * 512;
  float* rho_inv    = partials + 1024;  // 128 floats (old slot-2 space)

  dim3 blk(256);

  // 1) fused projections: q -> out0, k -> out1, raw vals -> ws
  gemm_mfma<true, false><<<dim3(6, 256, 1), blk, 0, stream>>>(
      x, Wq, out0, 0, 0, 0, bq, nullptr, 0, 0, nullptr, nullptr,
      Wk, bk, out1, Wv, vals_buf, nullptr, nullptr);

  // 2) scores = q @ k^T -> ws (fp32), per-tile norm^2 -> slot 0
  gemm_mfma<true, true><<<dim3(512, 1, 1), blk, 0, stream>>>(
      out0, out1, scores_buf, MAT, MAT, MAT, nullptr, nullptr, 0, 0, partials,
      nullptr, nullptr, nullptr, nullptr, nullptr, nullptr, nullptr, nullptr);

  // 3) sigma power iteration
  sigma_kernel<<<1, dim3(1024), 0, stream>>>(Wv, u0, sigma);

  // 4) squaring 1: S (fp32, split) -> bf16 M1 in out0s, norm slot 1
  sq_f32bf<<<dim3(512, 1, 1), blk, 0, stream>>>(scores_buf, out0s, partials, partials + 512);

  // 5) squarings 2..12 fused, LDS-resident; writes rho_inv[bz]
  chain_fused<<<dim3(128, 1, 1), dim3(512, 1, 1), 0, stream>>>(out0s, partials, rho_inv);

  // 6) final: weighted = (S @ (vals/sigma + bv)) * rho_inv -> out0,
  //    attention = S * rho_inv -> out1 (A-staging). alpha = rho_inv[bz] (smode 2).
  gemm_mfma<false, true><<<dim3(512, 1, 1), blk, 0, stream>>>(
      scores_buf, vals_buf, out0, MAT, MAT, MAT, nullptr, rho_inv, 1, 2, nullptr,
      out1, nullptr, nullptr, nullptr, nullptr, nullptr, sigma, bv);
}